// Round 1
// baseline (1959.059 us; speedup 1.0000x reference)
//
#include <hip/hip_runtime.h>
#include <hip/hip_bf16.h>
#include <math.h>

// Problem constants (from the reference)
#define BS    4
#define QLEN  2048
#define DIM   1024
#define NH    16
#define DH    64
#define MROWS (BS * QLEN)          // 8192 rows in the projection GEMMs

// GEMM tiling: 128x128 tile, BK=16, 256 threads, 8x8 acc per thread
#define BM 128
#define BN 128
#define BK 16
#define LDSP (BM + 4)              // padded leading dim for LDS tiles

// ---------------------------------------------------------------------------
// Fused QKV projection:  out = (x @ W^T + b) [* 1/sqrt(DH) for Q]
// A = x [MROWS][DIM] row-major, B = W [DIM][DIM] row-major (used transposed).
// Output written scattered into per-head layout: [b][h][q][d].
// blockIdx.z in {0,1,2} selects {Q,K,V}.
// ---------------------------------------------------------------------------
__global__ __launch_bounds__(256, 2)
void gemm_qkv(const float* __restrict__ x,
              const float* __restrict__ wq, const float* __restrict__ bq,
              const float* __restrict__ wk, const float* __restrict__ bk,
              const float* __restrict__ wv, const float* __restrict__ bv,
              float* __restrict__ qout, float* __restrict__ kout,
              float* __restrict__ vout)
{
    const int which = blockIdx.z;
    const float* __restrict__ W    = (which == 0) ? wq : (which == 1) ? wk : wv;
    const float* __restrict__ bias = (which == 0) ? bq : (which == 1) ? bk : bv;
    float* __restrict__ out        = (which == 0) ? qout : (which == 1) ? kout : vout;
    const float scale = (which == 0) ? 0.125f : 1.0f;   // 1/sqrt(64) for Q

    __shared__ float As[BK][LDSP];   // A-tile transposed: [k][m]
    __shared__ float Bs[BK][LDSP];   // B-tile transposed: [k][n]

    const int tid = threadIdx.x;
    const int tr = tid >> 4;         // 0..15
    const int tc = tid & 15;         // 0..15
    const int m0 = blockIdx.x * BM;
    const int n0 = blockIdx.y * BN;

    float acc[8][8];
    #pragma unroll
    for (int i = 0; i < 8; ++i)
        #pragma unroll
        for (int j = 0; j < 8; ++j) acc[i][j] = 0.0f;

    for (int k0 = 0; k0 < DIM; k0 += BK) {
        // stage A-tile (128x16) and B-tile (128x16), transposed into LDS
        #pragma unroll
        for (int it = 0; it < 2; ++it) {
            const int f   = it * 256 + tid;   // 0..511 float4 slots
            const int row = f >> 2;           // 4 float4 per 16-float row
            const int kg  = (f & 3) * 4;
            float4 a = *reinterpret_cast<const float4*>(
                &x[(size_t)(m0 + row) * DIM + k0 + kg]);
            As[kg + 0][row] = a.x; As[kg + 1][row] = a.y;
            As[kg + 2][row] = a.z; As[kg + 3][row] = a.w;
            float4 b = *reinterpret_cast<const float4*>(
                &W[(size_t)(n0 + row) * DIM + k0 + kg]);
            Bs[kg + 0][row] = b.x; Bs[kg + 1][row] = b.y;
            Bs[kg + 2][row] = b.z; Bs[kg + 3][row] = b.w;
        }
        __syncthreads();

        #pragma unroll
        for (int kk = 0; kk < BK; ++kk) {
            float4 a0 = *reinterpret_cast<const float4*>(&As[kk][tr * 4]);
            float4 a1 = *reinterpret_cast<const float4*>(&As[kk][tr * 4 + 64]);
            float4 b0 = *reinterpret_cast<const float4*>(&Bs[kk][tc * 4]);
            float4 b1 = *reinterpret_cast<const float4*>(&Bs[kk][tc * 4 + 64]);
            float av[8] = {a0.x, a0.y, a0.z, a0.w, a1.x, a1.y, a1.z, a1.w};
            float bv2[8] = {b0.x, b0.y, b0.z, b0.w, b1.x, b1.y, b1.z, b1.w};
            #pragma unroll
            for (int i = 0; i < 8; ++i)
                #pragma unroll
                for (int j = 0; j < 8; ++j)
                    acc[i][j] = fmaf(av[i], bv2[j], acc[i][j]);
        }
        __syncthreads();
    }

    // epilogue: bias, scale, scatter to [b][h][q][d]
    #pragma unroll
    for (int ib = 0; ib < 2; ++ib) {
        #pragma unroll
        for (int ii = 0; ii < 4; ++ii) {
            const int row  = m0 + ib * 64 + tr * 4 + ii;
            const int bidx = row >> 11;          // / QLEN
            const int qidx = row & (QLEN - 1);
            #pragma unroll
            for (int jb = 0; jb < 2; ++jb) {
                const int col = n0 + jb * 64 + tc * 4;
                const int hh = col >> 6;
                const int dd = col & 63;
                float4 b4 = *reinterpret_cast<const float4*>(&bias[col]);
                float4 r;
                r.x = (acc[ib * 4 + ii][jb * 4 + 0] + b4.x) * scale;
                r.y = (acc[ib * 4 + ii][jb * 4 + 1] + b4.y) * scale;
                r.z = (acc[ib * 4 + ii][jb * 4 + 2] + b4.z) * scale;
                r.w = (acc[ib * 4 + ii][jb * 4 + 3] + b4.w) * scale;
                *reinterpret_cast<float4*>(
                    &out[(((size_t)bidx * NH + hh) * QLEN + qidx) * DH + dd]) = r;
            }
        }
    }
}

// ---------------------------------------------------------------------------
// Output projection: out = ctx @ wo^T + bo   (plain row-major in/out)
// ---------------------------------------------------------------------------
__global__ __launch_bounds__(256, 2)
void gemm_out(const float* __restrict__ A,
              const float* __restrict__ W, const float* __restrict__ bias,
              float* __restrict__ out)
{
    __shared__ float As[BK][LDSP];
    __shared__ float Bs[BK][LDSP];

    const int tid = threadIdx.x;
    const int tr = tid >> 4;
    const int tc = tid & 15;
    const int m0 = blockIdx.x * BM;
    const int n0 = blockIdx.y * BN;

    float acc[8][8];
    #pragma unroll
    for (int i = 0; i < 8; ++i)
        #pragma unroll
        for (int j = 0; j < 8; ++j) acc[i][j] = 0.0f;

    for (int k0 = 0; k0 < DIM; k0 += BK) {
        #pragma unroll
        for (int it = 0; it < 2; ++it) {
            const int f   = it * 256 + tid;
            const int row = f >> 2;
            const int kg  = (f & 3) * 4;
            float4 a = *reinterpret_cast<const float4*>(
                &A[(size_t)(m0 + row) * DIM + k0 + kg]);
            As[kg + 0][row] = a.x; As[kg + 1][row] = a.y;
            As[kg + 2][row] = a.z; As[kg + 3][row] = a.w;
            float4 b = *reinterpret_cast<const float4*>(
                &W[(size_t)(n0 + row) * DIM + k0 + kg]);
            Bs[kg + 0][row] = b.x; Bs[kg + 1][row] = b.y;
            Bs[kg + 2][row] = b.z; Bs[kg + 3][row] = b.w;
        }
        __syncthreads();

        #pragma unroll
        for (int kk = 0; kk < BK; ++kk) {
            float4 a0 = *reinterpret_cast<const float4*>(&As[kk][tr * 4]);
            float4 a1 = *reinterpret_cast<const float4*>(&As[kk][tr * 4 + 64]);
            float4 b0 = *reinterpret_cast<const float4*>(&Bs[kk][tc * 4]);
            float4 b1 = *reinterpret_cast<const float4*>(&Bs[kk][tc * 4 + 64]);
            float av[8] = {a0.x, a0.y, a0.z, a0.w, a1.x, a1.y, a1.z, a1.w};
            float bv2[8] = {b0.x, b0.y, b0.z, b0.w, b1.x, b1.y, b1.z, b1.w};
            #pragma unroll
            for (int i = 0; i < 8; ++i)
                #pragma unroll
                for (int j = 0; j < 8; ++j)
                    acc[i][j] = fmaf(av[i], bv2[j], acc[i][j]);
        }
        __syncthreads();
    }

    #pragma unroll
    for (int ib = 0; ib < 2; ++ib) {
        #pragma unroll
        for (int ii = 0; ii < 4; ++ii) {
            const int row = m0 + ib * 64 + tr * 4 + ii;
            #pragma unroll
            for (int jb = 0; jb < 2; ++jb) {
                const int col = n0 + jb * 64 + tc * 4;
                float4 b4 = *reinterpret_cast<const float4*>(&bias[col]);
                float4 r;
                r.x = acc[ib * 4 + ii][jb * 4 + 0] + b4.x;
                r.y = acc[ib * 4 + ii][jb * 4 + 1] + b4.y;
                r.z = acc[ib * 4 + ii][jb * 4 + 2] + b4.z;
                r.w = acc[ib * 4 + ii][jb * 4 + 3] + b4.w;
                *reinterpret_cast<float4*>(&out[(size_t)row * DIM + col]) = r;
            }
        }
    }
}

// ---------------------------------------------------------------------------
// Flash attention (fp32, online softmax). One block = one (b,h) x 64 Q-rows.
// Q pre-scaled by 1/sqrt(DH) in the projection.
// Thread grid 16x16: thread (tr,tc) owns S[4tr+i][4tc+j] and O[4tr+i][4tc+j].
// ---------------------------------------------------------------------------
__global__ __launch_bounds__(256, 2)
void flash_attn(const float* __restrict__ q, const float* __restrict__ k,
                const float* __restrict__ v, const int* __restrict__ mask,
                float* __restrict__ ctx)
{
    const int bh = blockIdx.y;            // 0..BS*NH-1
    const int b  = bh / NH;
    const int h  = bh % NH;
    const int q0 = blockIdx.x * 64;
    const int tid = threadIdx.x;
    const int tr = tid >> 4;
    const int tc = tid & 15;

    __shared__ float Qs[DH][64 + 4];      // [d][q-row]  (transposed)
    __shared__ float Ks[DH][64 + 4];      // [d][k-col]  (transposed)
    __shared__ float Vs[64][DH + 4];      // [k][d]      (natural)
    __shared__ float Ps[64][64 + 4];      // [k][q-row]  (transposed)
    __shared__ float mneg[64];            // 0 or -1e30 per key of this tile

    const float* __restrict__ Qh = q + (size_t)bh * QLEN * DH;
    const float* __restrict__ Kh = k + (size_t)bh * QLEN * DH;
    const float* __restrict__ Vh = v + (size_t)bh * QLEN * DH;

    // load Q-tile (64x64) transposed into LDS; 4 float4 per thread
    #pragma unroll
    for (int it = 0; it < 4; ++it) {
        const int f   = it * 256 + tid;    // 0..1023 float4 slots
        const int row = f >> 4;            // 16 float4 per 64-float row
        const int dg  = (f & 15) * 4;
        float4 a = *reinterpret_cast<const float4*>(
            &Qh[(size_t)(q0 + row) * DH + dg]);
        Qs[dg + 0][row] = a.x; Qs[dg + 1][row] = a.y;
        Qs[dg + 2][row] = a.z; Qs[dg + 3][row] = a.w;
    }

    float o[4][4] = {{0.f}};
    float mrow[4] = {-INFINITY, -INFINITY, -INFINITY, -INFINITY};
    float lrow[4] = {0.f, 0.f, 0.f, 0.f};

    __syncthreads();

    for (int kt = 0; kt < QLEN; kt += 64) {
        // stage K-tile transposed + V-tile natural
        #pragma unroll
        for (int it = 0; it < 4; ++it) {
            const int f   = it * 256 + tid;
            const int row = f >> 4;
            const int dg  = (f & 15) * 4;
            float4 a = *reinterpret_cast<const float4*>(
                &Kh[(size_t)(kt + row) * DH + dg]);
            Ks[dg + 0][row] = a.x; Ks[dg + 1][row] = a.y;
            Ks[dg + 2][row] = a.z; Ks[dg + 3][row] = a.w;
            float4 b2 = *reinterpret_cast<const float4*>(
                &Vh[(size_t)(kt + row) * DH + dg]);
            *reinterpret_cast<float4*>(&Vs[row][dg]) = b2;
        }
        if (tid < 64)
            mneg[tid] = (mask[b * QLEN + kt + tid] == 0) ? -1e30f : 0.0f;
        __syncthreads();

        // S = Q K^T for this tile (outer-product over d)
        float s[4][4] = {{0.f}};
        #pragma unroll 16
        for (int d = 0; d < DH; ++d) {
            float4 qa = *reinterpret_cast<const float4*>(&Qs[d][tr * 4]);
            float4 ka = *reinterpret_cast<const float4*>(&Ks[d][tc * 4]);
            float qv[4] = {qa.x, qa.y, qa.z, qa.w};
            float kv[4] = {ka.x, ka.y, ka.z, ka.w};
            #pragma unroll
            for (int i = 0; i < 4; ++i)
                #pragma unroll
                for (int j = 0; j < 4; ++j)
                    s[i][j] = fmaf(qv[i], kv[j], s[i][j]);
        }
        #pragma unroll
        for (int i = 0; i < 4; ++i)
            #pragma unroll
            for (int j = 0; j < 4; ++j)
                s[i][j] += mneg[tc * 4 + j];

        // online softmax: per-q-row stats; rows of thread = 4tr+i, the 16
        // lanes sharing tr are consecutive -> shuffle-reduce width 16
        #pragma unroll
        for (int i = 0; i < 4; ++i) {
            float pm = fmaxf(fmaxf(s[i][0], s[i][1]), fmaxf(s[i][2], s[i][3]));
            #pragma unroll
            for (int off = 1; off < 16; off <<= 1)
                pm = fmaxf(pm, __shfl_xor(pm, off, 16));
            const float mnew  = fmaxf(mrow[i], pm);
            const float resc  = __expf(mrow[i] - mnew);
            float ps = 0.f;
            #pragma unroll
            for (int j = 0; j < 4; ++j) {
                const float p = __expf(s[i][j] - mnew);
                s[i][j] = p;
                ps += p;
            }
            #pragma unroll
            for (int off = 1; off < 16; off <<= 1)
                ps += __shfl_xor(ps, off, 16);
            lrow[i] = lrow[i] * resc + ps;
            mrow[i] = mnew;
            #pragma unroll
            for (int j = 0; j < 4; ++j) o[i][j] *= resc;
        }

        // write P transposed: Ps[k-col][q-row]
        #pragma unroll
        for (int i = 0; i < 4; ++i)
            #pragma unroll
            for (int j = 0; j < 4; ++j)
                Ps[tc * 4 + j][tr * 4 + i] = s[i][j];
        __syncthreads();

        // O += P V
        #pragma unroll 16
        for (int kk = 0; kk < 64; ++kk) {
            float4 pa = *reinterpret_cast<const float4*>(&Ps[kk][tr * 4]);
            float4 va = *reinterpret_cast<const float4*>(&Vs[kk][tc * 4]);
            float pv[4] = {pa.x, pa.y, pa.z, pa.w};
            float vv[4] = {va.x, va.y, va.z, va.w};
            #pragma unroll
            for (int i = 0; i < 4; ++i)
                #pragma unroll
                for (int j = 0; j < 4; ++j)
                    o[i][j] = fmaf(pv[i], vv[j], o[i][j]);
        }
        __syncthreads();   // protect Ks/Vs/Ps before next stage
    }

    // normalize + write ctx in [b][q][dim] row-major
    #pragma unroll
    for (int i = 0; i < 4; ++i) {
        const float inv = 1.0f / lrow[i];
        const int qrow = q0 + tr * 4 + i;
        float4 r;
        r.x = o[i][0] * inv; r.y = o[i][1] * inv;
        r.z = o[i][2] * inv; r.w = o[i][3] * inv;
        *reinterpret_cast<float4*>(
            &ctx[((size_t)b * QLEN + qrow) * DIM + h * DH + tc * 4]) = r;
    }
}

// ---------------------------------------------------------------------------
extern "C" void kernel_launch(void* const* d_in, const int* in_sizes, int n_in,
                              void* d_out, int out_size, void* d_ws, size_t ws_size,
                              hipStream_t stream)
{
    const float* x    = (const float*)d_in[0];
    const int*   mask = (const int*)  d_in[1];
    const float* wq   = (const float*)d_in[2];
    const float* bq   = (const float*)d_in[3];
    const float* wk   = (const float*)d_in[4];
    const float* bk   = (const float*)d_in[5];
    const float* wv   = (const float*)d_in[6];
    const float* bv   = (const float*)d_in[7];
    const float* wo   = (const float*)d_in[8];
    const float* bo   = (const float*)d_in[9];
    float* out = (float*)d_out;

    float* ws = (float*)d_ws;
    const size_t S = (size_t)MROWS * DIM;      // 8.39M floats per buffer
    float* qb  = ws;
    float* kb  = ws + S;
    float* vb  = ws + 2 * S;
    float* ctx = ws + 3 * S;

    // 1) fused QKV projections (z selects Q/K/V)
    dim3 gq(MROWS / BM, DIM / BN, 3);
    gemm_qkv<<<gq, 256, 0, stream>>>(x, wq, bq, wk, bk, wv, bv, qb, kb, vb);

    // 2) flash attention
    dim3 gf(QLEN / 64, BS * NH);
    flash_attn<<<gf, 256, 0, stream>>>(qb, kb, vb, mask, ctx);

    // 3) output projection
    dim3 go(MROWS / BM, DIM / BN);
    gemm_out<<<go, 256, 0, stream>>>(ctx, wo, bo, out);
}

// Round 5
// 646.769 us; speedup vs baseline: 3.0290x; 3.0290x over previous
//
#include <hip/hip_runtime.h>
#include <hip/hip_bf16.h>
#include <math.h>

// Problem constants (from the reference)
#define BS    4
#define QLEN  2048
#define DIM   1024
#define NH    16
#define DH    64
#define MROWS (BS * QLEN)          // 8192 rows in the projection GEMMs

typedef short  bf16x8 __attribute__((ext_vector_type(8)));  // 8 bf16 (4 VGPRs)
typedef short  bf16x4 __attribute__((ext_vector_type(4)));  // 4 bf16 (8B)
typedef float  f32x4  __attribute__((ext_vector_type(4)));  // MFMA acc

// float -> bf16 (round-to-nearest-even), bit pattern in a short
static __device__ __forceinline__ short f2bf(float f) {
    union { float f; unsigned u; } x; x.f = f;
    unsigned r = (x.u + 0x7fffu + ((x.u >> 16) & 1u)) >> 16;
    return (short)r;
}

// ===========================================================================
// bf16-MFMA GEMM core (shared by both projection kernels):
//   C(128x128) = A(128xK) . B(128xK)^T   with A,B fp32 in HBM, converted to
//   bf16 at LDS-staging time, fp32 MFMA accumulate.
// Tiles: BK=64, single-buffered LDS [128][72] bf16 (144B row stride = 36
// dwords -> bank stride 4 -> 2-way conflicts = free on ds_read_b128).
// Staging: 8 iters x 256 threads = 2048 float4 = full 128x64 tile per matrix
// (R4 fix: the R3 version staged only 16 of 64 k-columns).
// 4 waves (2x2); wave (wr,wc) owns a 64x64 output quadrant as 4x4 MFMA
// fragments. MFMA 16x16x32 layouts (m89/m91-verified D; A/B std CDNA):
//   a[j]=A[l&15][(l>>4)*8+j], b[j]=Bs[l&15][(l>>4)*8+j],
//   d[r]=D[(l>>4)*4+r][l&15].
// ===========================================================================
#define GEMM_MFMA_CORE(APTR, BPTR)                                            \
    __shared__ short As[128][72];                                             \
    __shared__ short Bs[128][72];                                             \
    const int tid = threadIdx.x;                                              \
    const int w   = tid >> 6;                                                 \
    const int l   = tid & 63;                                                 \
    const int g   = l >> 4;                                                   \
    const int l15 = l & 15;                                                   \
    const int wr  = w >> 1;                                                   \
    const int wc  = w & 1;                                                    \
    const int m0  = blockIdx.x * 128;                                         \
    const int n0  = blockIdx.y * 128;                                         \
    f32x4 acc[4][4];                                                          \
    _Pragma("unroll")                                                         \
    for (int m = 0; m < 4; ++m)                                               \
        _Pragma("unroll")                                                     \
        for (int n = 0; n < 4; ++n) acc[m][n] = (f32x4){0.f, 0.f, 0.f, 0.f}; \
    for (int k0 = 0; k0 < DIM; k0 += 64) {                                    \
        __syncthreads();                                                      \
        _Pragma("unroll")                                                     \
        for (int it = 0; it < 8; ++it) {                                      \
            const int s   = it * 256 + tid;      /* 0..2047 float4 slots */   \
            const int row = s >> 4;              /* 16 float4 per 64-col row*/\
            const int f4  = (s & 15) * 4;                                     \
            float4 a = *reinterpret_cast<const float4*>(                      \
                &APTR[(size_t)(m0 + row) * DIM + k0 + f4]);                   \
            bf16x4 av;                                                        \
            av[0] = f2bf(a.x); av[1] = f2bf(a.y);                             \
            av[2] = f2bf(a.z); av[3] = f2bf(a.w);                             \
            *reinterpret_cast<bf16x4*>(&As[row][f4]) = av;                    \
            float4 b = *reinterpret_cast<const float4*>(                      \
                &BPTR[(size_t)(n0 + row) * DIM + k0 + f4]);                   \
            bf16x4 bw;                                                        \
            bw[0] = f2bf(b.x); bw[1] = f2bf(b.y);                             \
            bw[2] = f2bf(b.z); bw[3] = f2bf(b.w);                             \
            *reinterpret_cast<bf16x4*>(&Bs[row][f4]) = bw;                    \
        }                                                                     \
        __syncthreads();                                                      \
        _Pragma("unroll")                                                     \
        for (int ks = 0; ks < 2; ++ks) {                                      \
            bf16x8 af[4], bfv[4];                                             \
            _Pragma("unroll")                                                 \
            for (int m = 0; m < 4; ++m)                                       \
                af[m] = *reinterpret_cast<const bf16x8*>(                     \
                    &As[wr * 64 + m * 16 + l15][ks * 32 + g * 8]);            \
            _Pragma("unroll")                                                 \
            for (int n = 0; n < 4; ++n)                                       \
                bfv[n] = *reinterpret_cast<const bf16x8*>(                    \
                    &Bs[wc * 64 + n * 16 + l15][ks * 32 + g * 8]);            \
            _Pragma("unroll")                                                 \
            for (int m = 0; m < 4; ++m)                                       \
                _Pragma("unroll")                                             \
                for (int n = 0; n < 4; ++n)                                   \
                    acc[m][n] = __builtin_amdgcn_mfma_f32_16x16x32_bf16(      \
                        af[m], bfv[n], acc[m][n], 0, 0, 0);                   \
        }                                                                     \
    }

// ---------------------------------------------------------------------------
// Fused QKV projection: out = (x @ W^T + b) [* 1/sqrt(DH) for Q], scattered
// into per-head layout [b][h][q][d]. blockIdx.z selects {Q,K,V}.
// ---------------------------------------------------------------------------
__global__ __launch_bounds__(256, 2)
void gemm_qkv_mfma(const float* __restrict__ x,
                   const float* __restrict__ wq, const float* __restrict__ bq,
                   const float* __restrict__ wk, const float* __restrict__ bk,
                   const float* __restrict__ wv, const float* __restrict__ bv,
                   float* __restrict__ qout, float* __restrict__ kout,
                   float* __restrict__ vout)
{
    const int which = blockIdx.z;
    const float* __restrict__ W    = (which == 0) ? wq : (which == 1) ? wk : wv;
    const float* __restrict__ bias = (which == 0) ? bq : (which == 1) ? bk : bv;
    float* __restrict__ out        = (which == 0) ? qout : (which == 1) ? kout : vout;
    const float scale = (which == 0) ? 0.125f : 1.0f;   // 1/sqrt(64) for Q

    GEMM_MFMA_CORE(x, W)

    // epilogue: bias + scale, scatter to [b][h][q][d]
    const int h = (n0 + wc * 64) >> 6;     // head is constant per wave quadrant
    #pragma unroll
    for (int n = 0; n < 4; ++n) {
        const int dd = n * 16 + l15;
        const float bn = bias[(h << 6) + dd];
        #pragma unroll
        for (int m = 0; m < 4; ++m) {
            #pragma unroll
            for (int r = 0; r < 4; ++r) {
                const int row = m0 + wr * 64 + m * 16 + g * 4 + r;
                const int bb  = row >> 11;           // / QLEN
                const int qq  = row & (QLEN - 1);
                out[(((size_t)bb * NH + h) * QLEN + qq) * DH + dd] =
                    (acc[m][n][r] + bn) * scale;
            }
        }
    }
}

// ---------------------------------------------------------------------------
// Output projection: out = ctx @ wo^T + bo  (row-major out)
// ---------------------------------------------------------------------------
__global__ __launch_bounds__(256, 2)
void gemm_out_mfma(const float* __restrict__ A,
                   const float* __restrict__ W, const float* __restrict__ bias,
                   float* __restrict__ out)
{
    GEMM_MFMA_CORE(A, W)

    #pragma unroll
    for (int n = 0; n < 4; ++n) {
        const int col  = n0 + wc * 64 + n * 16 + l15;
        const float bn = bias[col];
        #pragma unroll
        for (int m = 0; m < 4; ++m) {
            #pragma unroll
            for (int r = 0; r < 4; ++r) {
                const int row = m0 + wr * 64 + m * 16 + g * 4 + r;
                out[(size_t)row * DIM + col] = acc[m][n][r] + bn;
            }
        }
    }
}

// ---------------------------------------------------------------------------
// Flash attention, bf16 MFMA (16x16x32), fp32 accumulate, online softmax.
// Block = 256 threads (4 waves). Wave w owns q-rows [q0+16w, q0+16w+16).
// KV tiles of 64 keys staged in LDS as bf16, rows padded to 72 (144B: bank
// stride 4 mod 32 -> <=2-way conflicts, 16B-aligned for ds_read_b128).
//
// Per tile:
//   S^T = K_tile(64x64) . Q_w^T(64x16)  -- swapped operands so each lane
//         holds 16 scores of ONE q-row (l&15): frag mf, reg r -> key
//         mf*16 + (l>>4)*4 + r. Row softmax = in-lane(16) + shfl_xor 16,32.
//   P (bf16) -> per-wave LDS buffer (D-layout write b64, A-layout read b128).
//   O += P(16x64) . V(64x64) with V read from transposed LDS tile (b128).
// ---------------------------------------------------------------------------
__global__ __launch_bounds__(256, 4)
void flash_attn_mfma(const float* __restrict__ q, const float* __restrict__ k,
                     const float* __restrict__ v, const int* __restrict__ mask,
                     float* __restrict__ ctx)
{
    const int bh = blockIdx.y;            // 0..BS*NH-1
    const int b  = bh >> 4;               // / NH
    const int h  = bh & 15;               // % NH
    const int q0 = blockIdx.x * 64;
    const int tid = threadIdx.x;
    const int w   = tid >> 6;             // wave 0..3
    const int l   = tid & 63;             // lane
    const int g   = l >> 4;               // 0..3
    const int l15 = l & 15;

    __shared__ short Ks[64][72];          // K tile  [key][d]   bf16, padded
    __shared__ short Vt[64][72];          // V tile  [d][key]   bf16, padded
    __shared__ short Ps[4][16][72];       // per-wave P [qrow][key] bf16
    __shared__ float mneg[64];            // 0 or -1e30 per key of this tile

    const float* __restrict__ Qh = q + (size_t)bh * QLEN * DH;
    const float* __restrict__ Kh = k + (size_t)bh * QLEN * DH;
    const float* __restrict__ Vh = v + (size_t)bh * QLEN * DH;

    // ---- Q B-fragments (held in registers for the whole kernel) ----
    bf16x8 qb[2];
    {
        const float* qp = Qh + (size_t)(q0 + w * 16 + l15) * DH;
        #pragma unroll
        for (int ks = 0; ks < 2; ++ks) {
            float4 f0 = *reinterpret_cast<const float4*>(qp + ks * 32 + g * 8);
            float4 f1 = *reinterpret_cast<const float4*>(qp + ks * 32 + g * 8 + 4);
            bf16x8 t;
            t[0] = f2bf(f0.x); t[1] = f2bf(f0.y); t[2] = f2bf(f0.z); t[3] = f2bf(f0.w);
            t[4] = f2bf(f1.x); t[5] = f2bf(f1.y); t[6] = f2bf(f1.z); t[7] = f2bf(f1.w);
            qb[ks] = t;
        }
    }

    f32x4 o[4];
    #pragma unroll
    for (int n = 0; n < 4; ++n) o[n] = (f32x4){0.f, 0.f, 0.f, 0.f};
    float m = -1e30f, lsum = 0.f;

    for (int kt = 0; kt < QLEN; kt += 64) {
        __syncthreads();   // previous tile's LDS reads complete

        // ---- stage K tile (natural) ----
        #pragma unroll
        for (int it = 0; it < 4; ++it) {
            const int c    = it * 256 + tid;
            const int row  = c >> 4;
            const int quad = c & 15;
            float4 a = *reinterpret_cast<const float4*>(
                &Kh[(size_t)(kt + row) * DH + quad * 4]);
            bf16x4 kw;
            kw[0] = f2bf(a.x); kw[1] = f2bf(a.y); kw[2] = f2bf(a.z); kw[3] = f2bf(a.w);
            *reinterpret_cast<bf16x4*>(&Ks[row][quad * 4]) = kw;
        }
        // ---- stage V tile transposed (4x4 block transpose per thread) ----
        {
            const int r0 = (tid & 15) * 4;   // V row block (key)
            const int c0 = (tid >> 4) * 4;   // V col block (d)
            float vm[4][4];
            #pragma unroll
            for (int i = 0; i < 4; ++i) {
                float4 a = *reinterpret_cast<const float4*>(
                    &Vh[(size_t)(kt + r0 + i) * DH + c0]);
                vm[i][0] = a.x; vm[i][1] = a.y; vm[i][2] = a.z; vm[i][3] = a.w;
            }
            #pragma unroll
            for (int j = 0; j < 4; ++j) {
                bf16x4 wv;
                wv[0] = f2bf(vm[0][j]); wv[1] = f2bf(vm[1][j]);
                wv[2] = f2bf(vm[2][j]); wv[3] = f2bf(vm[3][j]);
                *reinterpret_cast<bf16x4*>(&Vt[c0 + j][r0]) = wv;
            }
        }
        if (tid < 64)
            mneg[tid] = (mask[b * QLEN + kt + tid] == 0) ? -1e30f : 0.0f;
        __syncthreads();

        // ---- S^T = K . Q^T  (8 MFMAs) ----
        f32x4 s[4];
        #pragma unroll
        for (int mf = 0; mf < 4; ++mf) s[mf] = (f32x4){0.f, 0.f, 0.f, 0.f};
        #pragma unroll
        for (int mf = 0; mf < 4; ++mf) {
            #pragma unroll
            for (int ks = 0; ks < 2; ++ks) {
                bf16x8 a = *reinterpret_cast<const bf16x8*>(
                    &Ks[mf * 16 + l15][ks * 32 + g * 8]);
                s[mf] = __builtin_amdgcn_mfma_f32_16x16x32_bf16(a, qb[ks], s[mf], 0, 0, 0);
            }
        }

        // ---- mask + online softmax (row = l15, 16 keys per lane) ----
        float pm = -1e30f;
        #pragma unroll
        for (int mf = 0; mf < 4; ++mf)
            #pragma unroll
            for (int r = 0; r < 4; ++r) {
                s[mf][r] += mneg[mf * 16 + g * 4 + r];
                pm = fmaxf(pm, s[mf][r]);
            }
        pm = fmaxf(pm, __shfl_xor(pm, 16));
        pm = fmaxf(pm, __shfl_xor(pm, 32));
        const float mnew = fmaxf(m, pm);
        const float resc = __expf(m - mnew);
        float ps = 0.f;
        #pragma unroll
        for (int mf = 0; mf < 4; ++mf) {
            bf16x4 pw;
            #pragma unroll
            for (int r = 0; r < 4; ++r) {
                const float p = __expf(s[mf][r] - mnew);
                ps += p;
                pw[r] = f2bf(p);
            }
            *reinterpret_cast<bf16x4*>(&Ps[w][l15][mf * 16 + g * 4]) = pw;
        }
        ps += __shfl_xor(ps, 16);
        ps += __shfl_xor(ps, 32);
        lsum = lsum * resc + ps;
        m = mnew;

        // rescale O (acc rows are g*4+r; stats live at lane l15==row)
        float rs[4];
        #pragma unroll
        for (int r = 0; r < 4; ++r) rs[r] = __shfl(resc, g * 4 + r, 16);
        #pragma unroll
        for (int n = 0; n < 4; ++n)
            #pragma unroll
            for (int r = 0; r < 4; ++r) o[n][r] *= rs[r];

        // own-wave P writes must land before A-layout reads
        asm volatile("s_waitcnt lgkmcnt(0)" ::: "memory");

        // ---- O += P . V  (8 MFMAs) ----
        #pragma unroll
        for (int ks = 0; ks < 2; ++ks) {
            bf16x8 pa = *reinterpret_cast<const bf16x8*>(
                &Ps[w][l15][ks * 32 + g * 8]);
            #pragma unroll
            for (int n = 0; n < 4; ++n) {
                bf16x8 vb = *reinterpret_cast<const bf16x8*>(
                    &Vt[n * 16 + l15][ks * 32 + g * 8]);
                o[n] = __builtin_amdgcn_mfma_f32_16x16x32_bf16(pa, vb, o[n], 0, 0, 0);
            }
        }
    }

    // ---- epilogue: normalize, write ctx [b][q][dim] ----
    float ln[4];
    #pragma unroll
    for (int r = 0; r < 4; ++r) ln[r] = __shfl(lsum, g * 4 + r, 16);
    #pragma unroll
    for (int r = 0; r < 4; ++r) {
        const float inv  = 1.0f / ln[r];
        const int   qrow = q0 + w * 16 + g * 4 + r;
        #pragma unroll
        for (int n = 0; n < 4; ++n)
            ctx[((size_t)b * QLEN + qrow) * DIM + h * DH + n * 16 + l15] =
                o[n][r] * inv;
    }
}

// ---------------------------------------------------------------------------
extern "C" void kernel_launch(void* const* d_in, const int* in_sizes, int n_in,
                              void* d_out, int out_size, void* d_ws, size_t ws_size,
                              hipStream_t stream)
{
    const float* x    = (const float*)d_in[0];
    const int*   mask = (const int*)  d_in[1];
    const float* wq   = (const float*)d_in[2];
    const float* bq   = (const float*)d_in[3];
    const float* wk   = (const float*)d_in[4];
    const float* bk   = (const float*)d_in[5];
    const float* wv   = (const float*)d_in[6];
    const float* bv   = (const float*)d_in[7];
    const float* wo   = (const float*)d_in[8];
    const float* bo   = (const float*)d_in[9];
    float* out = (float*)d_out;

    float* ws = (float*)d_ws;
    const size_t S = (size_t)MROWS * DIM;
    float* qb  = ws;
    float* kb  = ws + S;
    float* vb  = ws + 2 * S;
    float* ctx = ws + 3 * S;

    // 1) fused QKV projections (z selects Q/K/V), bf16 MFMA
    dim3 gq(MROWS / 128, DIM / 128, 3);
    gemm_qkv_mfma<<<gq, 256, 0, stream>>>(x, wq, bq, wk, bk, wv, bv, qb, kb, vb);

    // 2) flash attention (bf16 MFMA)
    dim3 gf(QLEN / 64, BS * NH);
    flash_attn_mfma<<<gf, 256, 0, stream>>>(qb, kb, vb, mask, ctx);

    // 3) output projection, bf16 MFMA
    dim3 go(MROWS / 128, DIM / 128);
    gemm_out_mfma<<<go, 256, 0, stream>>>(ctx, wo, bo, out);
}

// Round 6
// 450.170 us; speedup vs baseline: 4.3518x; 1.4367x over previous
//
#include <hip/hip_runtime.h>
#include <hip/hip_bf16.h>
#include <math.h>

// Problem constants (from the reference)
#define BS    4
#define QLEN  2048
#define DIM   1024
#define NH    16
#define DH    64
#define MROWS (BS * QLEN)          // 8192 rows in the projection GEMMs

typedef short  bf16x8 __attribute__((ext_vector_type(8)));  // 8 bf16 (4 VGPRs)
typedef short  bf16x4 __attribute__((ext_vector_type(4)));  // 4 bf16 (8B)
typedef float  f32x4  __attribute__((ext_vector_type(4)));  // MFMA acc

// float -> bf16 (round-to-nearest-even), bit pattern in a short
static __device__ __forceinline__ short f2bf(float f) {
    union { float f; unsigned u; } x; x.f = f;
    unsigned r = (x.u + 0x7fffu + ((x.u >> 16) & 1u)) >> 16;
    return (short)r;
}

// ---------------------------------------------------------------------------
// Prepass: convert x and the 4 weight matrices fp32 -> bf16 once.
// (Replaces per-tile f2bf conversion in every GEMM K-step: R5 counters showed
// gemm staging latency/VALU-bound, MfmaUtil 8%.)
// ---------------------------------------------------------------------------
__global__ __launch_bounds__(256)
void cvt_bf16_all(const float* __restrict__ x,
                  const float* __restrict__ wq, const float* __restrict__ wk,
                  const float* __restrict__ wv, const float* __restrict__ wo,
                  short* __restrict__ xb, short* __restrict__ wqb,
                  short* __restrict__ wkb, short* __restrict__ wvb,
                  short* __restrict__ wob)
{
    const float* src; short* dst; int n;
    switch (blockIdx.y) {
        case 0:  src = x;  dst = xb;  n = MROWS * DIM; break;
        case 1:  src = wq; dst = wqb; n = DIM * DIM;   break;
        case 2:  src = wk; dst = wkb; n = DIM * DIM;   break;
        case 3:  src = wv; dst = wvb; n = DIM * DIM;   break;
        default: src = wo; dst = wob; n = DIM * DIM;   break;
    }
    for (int i = (blockIdx.x * 256 + threadIdx.x) * 8; i < n;
         i += gridDim.x * 256 * 8) {
        float4 a = *reinterpret_cast<const float4*>(src + i);
        float4 b = *reinterpret_cast<const float4*>(src + i + 4);
        bf16x8 t;
        t[0] = f2bf(a.x); t[1] = f2bf(a.y); t[2] = f2bf(a.z); t[3] = f2bf(a.w);
        t[4] = f2bf(b.x); t[5] = f2bf(b.y); t[6] = f2bf(b.z); t[7] = f2bf(b.w);
        *reinterpret_cast<bf16x8*>(dst + i) = t;
    }
}

// ===========================================================================
// bf16-MFMA GEMM core: C(128x128) = A(128xK) . B(128xK)^T, A,B bf16 in HBM.
// BK=64, single-buffered LDS [128][72] bf16 (144B stride -> bank stride 4 ->
// <=2-way conflicts = free on ds_read_b128 frag reads).
// Staging: 4 iters x 256 threads x 16B ushort8 load + ds_write_b128 per
// matrix = full 128x64 tile; no conversion VALU (prepass did it).
// 4 waves (2x2); wave (wr,wc) owns a 64x64 quadrant as 4x4 MFMA fragments.
// MFMA 16x16x32 layouts (m89/m91-verified D; A/B std CDNA):
//   a[j]=A[l&15][(l>>4)*8+j], b[j]=Bs[l&15][(l>>4)*8+j],
//   d[r]=D[(l>>4)*4+r][l&15].
// ===========================================================================
#define GEMM_CORE_BF16(APTR, BPTR)                                            \
    __shared__ short As[128][72];                                             \
    __shared__ short Bs[128][72];                                             \
    const int tid  = threadIdx.x;                                             \
    const int w    = tid >> 6;                                                \
    const int l    = tid & 63;                                                \
    const int g    = l >> 4;                                                  \
    const int l15  = l & 15;                                                  \
    const int wr   = w >> 1;                                                  \
    const int wc   = w & 1;                                                   \
    const int m0   = blockIdx.x * 128;                                        \
    const int n0   = blockIdx.y * 128;                                        \
    const int srow = tid >> 3;           /* 0..31 */                          \
    const int scol = (tid & 7) * 8;      /* 0..56, 16B-aligned */             \
    f32x4 acc[4][4];                                                          \
    _Pragma("unroll")                                                         \
    for (int m = 0; m < 4; ++m)                                               \
        _Pragma("unroll")                                                     \
        for (int n = 0; n < 4; ++n) acc[m][n] = (f32x4){0.f, 0.f, 0.f, 0.f}; \
    for (int k0 = 0; k0 < DIM; k0 += 64) {                                    \
        __syncthreads();                                                      \
        _Pragma("unroll")                                                     \
        for (int it = 0; it < 4; ++it) {                                      \
            const int row = it * 32 + srow;                                   \
            *reinterpret_cast<bf16x8*>(&As[row][scol]) =                      \
                *reinterpret_cast<const bf16x8*>(                             \
                    &APTR[(size_t)(m0 + row) * DIM + k0 + scol]);             \
            *reinterpret_cast<bf16x8*>(&Bs[row][scol]) =                      \
                *reinterpret_cast<const bf16x8*>(                             \
                    &BPTR[(size_t)(n0 + row) * DIM + k0 + scol]);             \
        }                                                                     \
        __syncthreads();                                                      \
        _Pragma("unroll")                                                     \
        for (int ks = 0; ks < 2; ++ks) {                                      \
            bf16x8 af[4], bfv[4];                                             \
            _Pragma("unroll")                                                 \
            for (int m = 0; m < 4; ++m)                                       \
                af[m] = *reinterpret_cast<const bf16x8*>(                     \
                    &As[wr * 64 + m * 16 + l15][ks * 32 + g * 8]);            \
            _Pragma("unroll")                                                 \
            for (int n = 0; n < 4; ++n)                                       \
                bfv[n] = *reinterpret_cast<const bf16x8*>(                    \
                    &Bs[wc * 64 + n * 16 + l15][ks * 32 + g * 8]);            \
            _Pragma("unroll")                                                 \
            for (int m = 0; m < 4; ++m)                                       \
                _Pragma("unroll")                                             \
                for (int n = 0; n < 4; ++n)                                   \
                    acc[m][n] = __builtin_amdgcn_mfma_f32_16x16x32_bf16(      \
                        af[m], bfv[n], acc[m][n], 0, 0, 0);                   \
        }                                                                     \
    }

// ---------------------------------------------------------------------------
// Fused QKV projection: out = (x @ W^T + b) [* 1/sqrt(DH) for Q], written as
// bf16 scattered into per-head layout [b][h][q][d]. blockIdx.z selects Q/K/V.
// ---------------------------------------------------------------------------
__global__ __launch_bounds__(256, 2)
void gemm_qkv_mfma(const short* __restrict__ xb,
                   const short* __restrict__ wqb, const float* __restrict__ bq,
                   const short* __restrict__ wkb, const float* __restrict__ bk,
                   const short* __restrict__ wvb, const float* __restrict__ bv,
                   short* __restrict__ qout, short* __restrict__ kout,
                   short* __restrict__ vout)
{
    const int which = blockIdx.z;
    const short* __restrict__ W    = (which == 0) ? wqb : (which == 1) ? wkb : wvb;
    const float* __restrict__ bias = (which == 0) ? bq  : (which == 1) ? bk  : bv;
    short* __restrict__ out        = (which == 0) ? qout : (which == 1) ? kout : vout;
    const float scale = (which == 0) ? 0.125f : 1.0f;   // 1/sqrt(64) for Q

    GEMM_CORE_BF16(xb, W)

    // epilogue: bias + scale, bf16 scatter to [b][h][q][d]
    const int h = (n0 + wc * 64) >> 6;     // head is constant per wave quadrant
    #pragma unroll
    for (int n = 0; n < 4; ++n) {
        const int dd = n * 16 + l15;
        const float bn = bias[(h << 6) + dd];
        #pragma unroll
        for (int m = 0; m < 4; ++m) {
            #pragma unroll
            for (int r = 0; r < 4; ++r) {
                const int row = m0 + wr * 64 + m * 16 + g * 4 + r;
                const int bb  = row >> 11;           // / QLEN
                const int qq  = row & (QLEN - 1);
                out[(((size_t)bb * NH + h) * QLEN + qq) * DH + dd] =
                    f2bf((acc[m][n][r] + bn) * scale);
            }
        }
    }
}

// ---------------------------------------------------------------------------
// Output projection: out = ctx @ wo^T + bo  (ctx bf16, out fp32 row-major)
// ---------------------------------------------------------------------------
__global__ __launch_bounds__(256, 2)
void gemm_out_mfma(const short* __restrict__ A,
                   const short* __restrict__ W, const float* __restrict__ bias,
                   float* __restrict__ out)
{
    GEMM_CORE_BF16(A, W)

    #pragma unroll
    for (int n = 0; n < 4; ++n) {
        const int col  = n0 + wc * 64 + n * 16 + l15;
        const float bn = bias[col];
        #pragma unroll
        for (int m = 0; m < 4; ++m) {
            #pragma unroll
            for (int r = 0; r < 4; ++r) {
                const int row = m0 + wr * 64 + m * 16 + g * 4 + r;
                out[(size_t)row * DIM + col] = acc[m][n][r] + bn;
            }
        }
    }
}

// ---------------------------------------------------------------------------
// Flash attention, bf16 MFMA (16x16x32), fp32 accumulate, online softmax.
// All inputs bf16 (from projection); staging is pure copy, no conversion.
// Block = 256 threads (4 waves). Wave w owns q-rows [q0+16w, q0+16w+16).
// KV tiles of 64 keys in LDS, rows padded to 72 shorts (<=2-way conflicts).
// ---------------------------------------------------------------------------
__global__ __launch_bounds__(256, 4)
void flash_attn_mfma(const short* __restrict__ q, const short* __restrict__ k,
                     const short* __restrict__ v, const int* __restrict__ mask,
                     short* __restrict__ ctx)
{
    const int bh = blockIdx.y;            // 0..BS*NH-1
    const int b  = bh >> 4;               // / NH
    const int h  = bh & 15;               // % NH
    const int q0 = blockIdx.x * 64;
    const int tid = threadIdx.x;
    const int w   = tid >> 6;             // wave 0..3
    const int l   = tid & 63;             // lane
    const int g   = l >> 4;               // 0..3
    const int l15 = l & 15;

    __shared__ short Ks[64][72];          // K tile  [key][d]   bf16, padded
    __shared__ short Vt[64][72];          // V tile  [d][key]   bf16, padded
    __shared__ short Ps[4][16][72];       // per-wave P [qrow][key] bf16
    __shared__ float mneg[64];            // 0 or -1e30 per key of this tile

    const short* __restrict__ Qh = q + (size_t)bh * QLEN * DH;
    const short* __restrict__ Kh = k + (size_t)bh * QLEN * DH;
    const short* __restrict__ Vh = v + (size_t)bh * QLEN * DH;

    // ---- Q B-fragments (bf16 direct loads, held for the whole kernel) ----
    bf16x8 qb[2];
    {
        const short* qp = Qh + (size_t)(q0 + w * 16 + l15) * DH;
        #pragma unroll
        for (int ks = 0; ks < 2; ++ks)
            qb[ks] = *reinterpret_cast<const bf16x8*>(qp + ks * 32 + g * 8);
    }

    f32x4 o[4];
    #pragma unroll
    for (int n = 0; n < 4; ++n) o[n] = (f32x4){0.f, 0.f, 0.f, 0.f};
    float m = -1e30f, lsum = 0.f;

    for (int kt = 0; kt < QLEN; kt += 64) {
        __syncthreads();   // previous tile's LDS reads complete

        // ---- stage K tile: 2 x (16B ushort8 copy) per thread ----
        #pragma unroll
        for (int it = 0; it < 2; ++it) {
            const int row  = it * 32 + (tid >> 3);
            const int col8 = (tid & 7) * 8;
            *reinterpret_cast<bf16x8*>(&Ks[row][col8]) =
                *reinterpret_cast<const bf16x8*>(
                    &Kh[(size_t)(kt + row) * DH + col8]);
        }
        // ---- stage V tile transposed (4x4 short-block transpose) ----
        {
            const int r0 = (tid & 15) * 4;   // V row block (key)
            const int c0 = (tid >> 4) * 4;   // V col block (d)
            bf16x4 vr[4];
            #pragma unroll
            for (int i = 0; i < 4; ++i)
                vr[i] = *reinterpret_cast<const bf16x4*>(
                    &Vh[(size_t)(kt + r0 + i) * DH + c0]);
            #pragma unroll
            for (int j = 0; j < 4; ++j) {
                bf16x4 wv = {vr[0][j], vr[1][j], vr[2][j], vr[3][j]};
                *reinterpret_cast<bf16x4*>(&Vt[c0 + j][r0]) = wv;
            }
        }
        if (tid < 64)
            mneg[tid] = (mask[b * QLEN + kt + tid] == 0) ? -1e30f : 0.0f;
        __syncthreads();

        // ---- S^T = K . Q^T  (8 MFMAs) ----
        f32x4 s[4];
        #pragma unroll
        for (int mf = 0; mf < 4; ++mf) s[mf] = (f32x4){0.f, 0.f, 0.f, 0.f};
        #pragma unroll
        for (int mf = 0; mf < 4; ++mf) {
            #pragma unroll
            for (int ks = 0; ks < 2; ++ks) {
                bf16x8 a = *reinterpret_cast<const bf16x8*>(
                    &Ks[mf * 16 + l15][ks * 32 + g * 8]);
                s[mf] = __builtin_amdgcn_mfma_f32_16x16x32_bf16(a, qb[ks], s[mf], 0, 0, 0);
            }
        }

        // ---- mask + online softmax (row = l15, 16 keys per lane) ----
        float pm = -1e30f;
        #pragma unroll
        for (int mf = 0; mf < 4; ++mf)
            #pragma unroll
            for (int r = 0; r < 4; ++r) {
                s[mf][r] += mneg[mf * 16 + g * 4 + r];
                pm = fmaxf(pm, s[mf][r]);
            }
        pm = fmaxf(pm, __shfl_xor(pm, 16));
        pm = fmaxf(pm, __shfl_xor(pm, 32));
        const float mnew = fmaxf(m, pm);
        const float resc = __expf(m - mnew);
        float ps = 0.f;
        #pragma unroll
        for (int mf = 0; mf < 4; ++mf) {
            bf16x4 pw;
            #pragma unroll
            for (int r = 0; r < 4; ++r) {
                const float p = __expf(s[mf][r] - mnew);
                ps += p;
                pw[r] = f2bf(p);
            }
            *reinterpret_cast<bf16x4*>(&Ps[w][l15][mf * 16 + g * 4]) = pw;
        }
        ps += __shfl_xor(ps, 16);
        ps += __shfl_xor(ps, 32);
        lsum = lsum * resc + ps;
        m = mnew;

        // rescale O (acc rows are g*4+r; stats live at lane l15==row)
        float rs[4];
        #pragma unroll
        for (int r = 0; r < 4; ++r) rs[r] = __shfl(resc, g * 4 + r, 16);
        #pragma unroll
        for (int n = 0; n < 4; ++n)
            #pragma unroll
            for (int r = 0; r < 4; ++r) o[n][r] *= rs[r];

        // own-wave P writes must land before A-layout reads
        asm volatile("s_waitcnt lgkmcnt(0)" ::: "memory");

        // ---- O += P . V  (8 MFMAs) ----
        #pragma unroll
        for (int ks = 0; ks < 2; ++ks) {
            bf16x8 pa = *reinterpret_cast<const bf16x8*>(
                &Ps[w][l15][ks * 32 + g * 8]);
            #pragma unroll
            for (int n = 0; n < 4; ++n) {
                bf16x8 vb = *reinterpret_cast<const bf16x8*>(
                    &Vt[n * 16 + l15][ks * 32 + g * 8]);
                o[n] = __builtin_amdgcn_mfma_f32_16x16x32_bf16(pa, vb, o[n], 0, 0, 0);
            }
        }
    }

    // ---- epilogue: normalize, write ctx (bf16) in [b][q][dim] ----
    float ln[4];
    #pragma unroll
    for (int r = 0; r < 4; ++r) ln[r] = __shfl(lsum, g * 4 + r, 16);
    #pragma unroll
    for (int r = 0; r < 4; ++r) {
        const float inv  = 1.0f / ln[r];
        const int   qrow = q0 + w * 16 + g * 4 + r;
        #pragma unroll
        for (int n = 0; n < 4; ++n)
            ctx[((size_t)b * QLEN + qrow) * DIM + h * DH + n * 16 + l15] =
                f2bf(o[n][r] * inv);
    }
}

// ---------------------------------------------------------------------------
extern "C" void kernel_launch(void* const* d_in, const int* in_sizes, int n_in,
                              void* d_out, int out_size, void* d_ws, size_t ws_size,
                              hipStream_t stream)
{
    const float* x    = (const float*)d_in[0];
    const int*   mask = (const int*)  d_in[1];
    const float* wq   = (const float*)d_in[2];
    const float* bq   = (const float*)d_in[3];
    const float* wk   = (const float*)d_in[4];
    const float* bk   = (const float*)d_in[5];
    const float* wv   = (const float*)d_in[6];
    const float* bv   = (const float*)d_in[7];
    const float* wo   = (const float*)d_in[8];
    const float* bo   = (const float*)d_in[9];
    float* out = (float*)d_out;

    short* ws = (short*)d_ws;
    const size_t S  = (size_t)MROWS * DIM;     // 8.39M elements
    const size_t W2 = (size_t)DIM * DIM;       // 1.05M elements
    short* xb   = ws;
    short* wqb  = xb  + S;
    short* wkb  = wqb + W2;
    short* wvb  = wkb + W2;
    short* wob  = wvb + W2;
    short* qb   = wob + W2;
    short* kb   = qb  + S;
    short* vb   = kb  + S;
    short* ctxb = vb  + S;

    // 0) one-time fp32 -> bf16 conversion of x and weights
    dim3 gc(512, 5);
    cvt_bf16_all<<<gc, 256, 0, stream>>>(x, wq, wk, wv, wo,
                                         xb, wqb, wkb, wvb, wob);

    // 1) fused QKV projections (z selects Q/K/V), bf16 in/out
    dim3 gq(MROWS / 128, DIM / 128, 3);
    gemm_qkv_mfma<<<gq, 256, 0, stream>>>(xb, wqb, bq, wkb, bk, wvb, bv,
                                          qb, kb, vb);

    // 2) flash attention (bf16 MFMA, bf16 in/out)
    dim3 gf(QLEN / 64, BS * NH);
    flash_attn_mfma<<<gf, 256, 0, stream>>>(qb, kb, vb, mask, ctxb);

    // 3) output projection (bf16 A/B, fp32 out)
    dim3 go(MROWS / 128, DIM / 128);
    gemm_out_mfma<<<go, 256, 0, stream>>>(ctxb, wob, bo, out);
}

// Round 10
// 356.687 us; speedup vs baseline: 5.4924x; 1.2621x over previous
//
#include <hip/hip_runtime.h>
#include <hip/hip_bf16.h>
#include <math.h>

// Problem constants (from the reference)
#define BS    4
#define QLEN  2048
#define DIM   1024
#define NH    16
#define DH    64
#define MROWS (BS * QLEN)          // 8192 rows in the projection GEMMs

typedef short  bf16x8 __attribute__((ext_vector_type(8)));  // 8 bf16 (4 VGPRs)
typedef short  bf16x4 __attribute__((ext_vector_type(4)));  // 4 bf16 (8B)
typedef float  f32x4  __attribute__((ext_vector_type(4)));  // MFMA acc

// float -> bf16 (round-to-nearest-even), bit pattern in a short
static __device__ __forceinline__ short f2bf(float f) {
    union { float f; unsigned u; } x; x.f = f;
    unsigned r = (x.u + 0x7fffu + ((x.u >> 16) & 1u)) >> 16;
    return (short)r;
}

// ---------------------------------------------------------------------------
// Prepass: convert x and the 4 weight matrices fp32 -> bf16 once.
// ---------------------------------------------------------------------------
__global__ __launch_bounds__(256)
void cvt_bf16_all(const float* __restrict__ x,
                  const float* __restrict__ wq, const float* __restrict__ wk,
                  const float* __restrict__ wv, const float* __restrict__ wo,
                  short* __restrict__ xb, short* __restrict__ wqb,
                  short* __restrict__ wkb, short* __restrict__ wvb,
                  short* __restrict__ wob)
{
    const float* src; short* dst; int n;
    switch (blockIdx.y) {
        case 0:  src = x;  dst = xb;  n = MROWS * DIM; break;
        case 1:  src = wq; dst = wqb; n = DIM * DIM;   break;
        case 2:  src = wk; dst = wkb; n = DIM * DIM;   break;
        case 3:  src = wv; dst = wvb; n = DIM * DIM;   break;
        default: src = wo; dst = wob; n = DIM * DIM;   break;
    }
    for (int i = (blockIdx.x * 256 + threadIdx.x) * 8; i < n;
         i += gridDim.x * 256 * 8) {
        float4 a = *reinterpret_cast<const float4*>(src + i);
        float4 b = *reinterpret_cast<const float4*>(src + i + 4);
        bf16x8 t;
        t[0] = f2bf(a.x); t[1] = f2bf(a.y); t[2] = f2bf(a.z); t[3] = f2bf(a.w);
        t[4] = f2bf(b.x); t[5] = f2bf(b.y); t[6] = f2bf(b.z); t[7] = f2bf(b.w);
        *reinterpret_cast<bf16x8*>(dst + i) = t;
    }
}

// ===========================================================================
// bf16-MFMA GEMM core with register prefetch (hide global latency).
// C(128x128) = A(128xK) . B(128xK)^T, A,B bf16 in HBM. BK=64.
// Per K-step: barrier -> ds_write prefetched regs -> issue next tile's
// global loads -> barrier -> 32 MFMAs.
// LDS [128][72] (144B stride -> <=2-way bank conflicts on b128 frag reads).
// 4 waves (2x2); wave (wr,wc) owns a 64x64 quadrant as 4x4 MFMA fragments.
// MFMA 16x16x32 layouts: a[j]=A[l&15][(l>>4)*8+j], b[j]=Bs[l&15][(l>>4)*8+j],
// d[r]=D[(l>>4)*4+r][l&15].
// ===========================================================================
#define GEMM_CORE_BF16(APTR, BPTR)                                            \
    __shared__ short As[128][72];                                             \
    __shared__ short Bs[128][72];                                             \
    const int tid  = threadIdx.x;                                             \
    const int w    = tid >> 6;                                                \
    const int l    = tid & 63;                                                \
    const int g    = l >> 4;                                                  \
    const int l15  = l & 15;                                                  \
    const int wr   = w >> 1;                                                  \
    const int wc   = w & 1;                                                   \
    const int m0   = blockIdx.x * 128;                                        \
    const int n0   = blockIdx.y * 128;                                        \
    const int srow = tid >> 3;           /* 0..31 */                          \
    const int scol = (tid & 7) * 8;      /* 0..56, 16B-aligned */             \
    bf16x8 ra[4], rb[4];                                                      \
    _Pragma("unroll")                                                         \
    for (int it = 0; it < 4; ++it) {                                          \
        const int row = it * 32 + srow;                                       \
        ra[it] = *reinterpret_cast<const bf16x8*>(                            \
            &APTR[(size_t)(m0 + row) * DIM + scol]);                          \
        rb[it] = *reinterpret_cast<const bf16x8*>(                            \
            &BPTR[(size_t)(n0 + row) * DIM + scol]);                          \
    }                                                                         \
    f32x4 acc[4][4];                                                          \
    _Pragma("unroll")                                                         \
    for (int m = 0; m < 4; ++m)                                               \
        _Pragma("unroll")                                                     \
        for (int n = 0; n < 4; ++n) acc[m][n] = (f32x4){0.f, 0.f, 0.f, 0.f}; \
    for (int k0 = 0; k0 < DIM; k0 += 64) {                                    \
        __syncthreads();                                                      \
        _Pragma("unroll")                                                     \
        for (int it = 0; it < 4; ++it) {                                      \
            const int row = it * 32 + srow;                                   \
            *reinterpret_cast<bf16x8*>(&As[row][scol]) = ra[it];              \
            *reinterpret_cast<bf16x8*>(&Bs[row][scol]) = rb[it];              \
        }                                                                     \
        if (k0 + 64 < DIM) {                                                  \
            _Pragma("unroll")                                                 \
            for (int it = 0; it < 4; ++it) {                                  \
                const int row = it * 32 + srow;                               \
                ra[it] = *reinterpret_cast<const bf16x8*>(                    \
                    &APTR[(size_t)(m0 + row) * DIM + k0 + 64 + scol]);        \
                rb[it] = *reinterpret_cast<const bf16x8*>(                    \
                    &BPTR[(size_t)(n0 + row) * DIM + k0 + 64 + scol]);        \
            }                                                                 \
        }                                                                     \
        __syncthreads();                                                      \
        _Pragma("unroll")                                                     \
        for (int ks = 0; ks < 2; ++ks) {                                      \
            bf16x8 af[4], bfv[4];                                             \
            _Pragma("unroll")                                                 \
            for (int m = 0; m < 4; ++m)                                       \
                af[m] = *reinterpret_cast<const bf16x8*>(                     \
                    &As[wr * 64 + m * 16 + l15][ks * 32 + g * 8]);            \
            _Pragma("unroll")                                                 \
            for (int n = 0; n < 4; ++n)                                       \
                bfv[n] = *reinterpret_cast<const bf16x8*>(                    \
                    &Bs[wc * 64 + n * 16 + l15][ks * 32 + g * 8]);            \
            _Pragma("unroll")                                                 \
            for (int m = 0; m < 4; ++m)                                       \
                _Pragma("unroll")                                             \
                for (int n = 0; n < 4; ++n)                                   \
                    acc[m][n] = __builtin_amdgcn_mfma_f32_16x16x32_bf16(      \
                        af[m], bfv[n], acc[m][n], 0, 0, 0);                   \
        }                                                                     \
    }

// ---------------------------------------------------------------------------
// Fused QKV projection: out = (x @ W^T + b) [* 1/sqrt(DH) for Q], written as
// bf16 scattered into per-head layout [b][h][q][d]. blockIdx.z selects Q/K/V.
// ---------------------------------------------------------------------------
__global__ __launch_bounds__(256, 2)
void gemm_qkv_mfma(const short* __restrict__ xb,
                   const short* __restrict__ wqb, const float* __restrict__ bq,
                   const short* __restrict__ wkb, const float* __restrict__ bk,
                   const short* __restrict__ wvb, const float* __restrict__ bv,
                   short* __restrict__ qout, short* __restrict__ kout,
                   short* __restrict__ vout)
{
    const int which = blockIdx.z;
    const short* __restrict__ W    = (which == 0) ? wqb : (which == 1) ? wkb : wvb;
    const float* __restrict__ bias = (which == 0) ? bq  : (which == 1) ? bk  : bv;
    short* __restrict__ out        = (which == 0) ? qout : (which == 1) ? kout : vout;
    const float scale = (which == 0) ? 0.125f : 1.0f;   // 1/sqrt(64) for Q

    GEMM_CORE_BF16(xb, W)

    // epilogue: bias + scale, bf16 scatter to [b][h][q][d]
    const int h = (n0 + wc * 64) >> 6;     // head is constant per wave quadrant
    #pragma unroll
    for (int n = 0; n < 4; ++n) {
        const int dd = n * 16 + l15;
        const float bn = bias[(h << 6) + dd];
        #pragma unroll
        for (int m = 0; m < 4; ++m) {
            #pragma unroll
            for (int r = 0; r < 4; ++r) {
                const int row = m0 + wr * 64 + m * 16 + g * 4 + r;
                const int bb  = row >> 11;           // / QLEN
                const int qq  = row & (QLEN - 1);
                out[(((size_t)bb * NH + h) * QLEN + qq) * DH + dd] =
                    f2bf((acc[m][n][r] + bn) * scale);
            }
        }
    }
}

// ---------------------------------------------------------------------------
// Output projection: out = ctx @ wo^T + bo  (ctx bf16, out fp32 row-major)
// ---------------------------------------------------------------------------
__global__ __launch_bounds__(256, 2)
void gemm_out_mfma(const short* __restrict__ A,
                   const short* __restrict__ W, const float* __restrict__ bias,
                   float* __restrict__ out)
{
    GEMM_CORE_BF16(A, W)

    #pragma unroll
    for (int n = 0; n < 4; ++n) {
        const int col  = n0 + wc * 64 + n * 16 + l15;
        const float bn = bias[col];
        #pragma unroll
        for (int m = 0; m < 4; ++m) {
            #pragma unroll
            for (int r = 0; r < 4; ++r) {
                const int row = m0 + wr * 64 + m * 16 + g * 4 + r;
                out[(size_t)row * DIM + col] = acc[m][n][r] + bn;
            }
        }
    }
}

// ===========================================================================
// Flash attention, bf16 MFMA, fp32 accumulate, online softmax.
// 128 q-rows/block (two 16-row halves per wave). R9 hardening vs R8:
//  - SEPARATE Ps buffer per half (no LDS write-after-read reuse in a tile)
//  - sched_barrier(0) after the lgkmcnt(0) fence (guide rule #18)
//  - no pointer-ternary selection of register arrays: half body is a macro
//    over explicitly-named registers (guide rule #20)
// Register-prefetched K/V staging retained.
// ===========================================================================
#define FLASH_HALF(QB, O, MREG, LREG, PS)                                     \
    {                                                                         \
        f32x4 s_[4];                                                          \
        _Pragma("unroll")                                                     \
        for (int mf = 0; mf < 4; ++mf) s_[mf] = (f32x4){0.f, 0.f, 0.f, 0.f};  \
        _Pragma("unroll")                                                     \
        for (int mf = 0; mf < 4; ++mf) {                                      \
            _Pragma("unroll")                                                 \
            for (int ks = 0; ks < 2; ++ks) {                                  \
                bf16x8 a_ = *reinterpret_cast<const bf16x8*>(                 \
                    &Ks[mf * 16 + l15][ks * 32 + g * 8]);                     \
                s_[mf] = __builtin_amdgcn_mfma_f32_16x16x32_bf16(             \
                    a_, QB[ks], s_[mf], 0, 0, 0);                             \
            }                                                                 \
        }                                                                     \
        float pm_ = -1e30f;                                                   \
        _Pragma("unroll")                                                     \
        for (int mf = 0; mf < 4; ++mf)                                        \
            _Pragma("unroll")                                                 \
            for (int r = 0; r < 4; ++r) {                                     \
                s_[mf][r] += mneg[mf * 16 + g * 4 + r];                       \
                pm_ = fmaxf(pm_, s_[mf][r]);                                  \
            }                                                                 \
        pm_ = fmaxf(pm_, __shfl_xor(pm_, 16));                                \
        pm_ = fmaxf(pm_, __shfl_xor(pm_, 32));                                \
        const float mnew_ = fmaxf(MREG, pm_);                                 \
        const float resc_ = __expf(MREG - mnew_);                             \
        float ps_ = 0.f;                                                      \
        _Pragma("unroll")                                                     \
        for (int mf = 0; mf < 4; ++mf) {                                      \
            bf16x4 pw_;                                                       \
            _Pragma("unroll")                                                 \
            for (int r = 0; r < 4; ++r) {                                     \
                const float p_ = __expf(s_[mf][r] - mnew_);                   \
                ps_ += p_;                                                    \
                pw_[r] = f2bf(p_);                                            \
            }                                                                 \
            *reinterpret_cast<bf16x4*>(&PS[w][l15][mf * 16 + g * 4]) = pw_;   \
        }                                                                     \
        ps_ += __shfl_xor(ps_, 16);                                           \
        ps_ += __shfl_xor(ps_, 32);                                           \
        LREG = LREG * resc_ + ps_;                                            \
        MREG = mnew_;                                                         \
        float rs_[4];                                                         \
        _Pragma("unroll")                                                     \
        for (int r = 0; r < 4; ++r) rs_[r] = __shfl(resc_, g * 4 + r, 16);    \
        _Pragma("unroll")                                                     \
        for (int n = 0; n < 4; ++n)                                           \
            _Pragma("unroll")                                                 \
            for (int r = 0; r < 4; ++r) O[n][r] *= rs_[r];                    \
        asm volatile("s_waitcnt lgkmcnt(0)" ::: "memory");                    \
        __builtin_amdgcn_sched_barrier(0);                                    \
        _Pragma("unroll")                                                     \
        for (int ks = 0; ks < 2; ++ks) {                                      \
            bf16x8 pa_ = *reinterpret_cast<const bf16x8*>(                    \
                &PS[w][l15][ks * 32 + g * 8]);                                \
            _Pragma("unroll")                                                 \
            for (int n = 0; n < 4; ++n) {                                     \
                bf16x8 vb_ = *reinterpret_cast<const bf16x8*>(                \
                    &Vt[n * 16 + l15][ks * 32 + g * 8]);                      \
                O[n] = __builtin_amdgcn_mfma_f32_16x16x32_bf16(               \
                    pa_, vb_, O[n], 0, 0, 0);                                 \
            }                                                                 \
        }                                                                     \
    }

__global__ __launch_bounds__(256, 4)
void flash_attn_mfma(const short* __restrict__ q, const short* __restrict__ k,
                     const short* __restrict__ v, const int* __restrict__ mask,
                     short* __restrict__ ctx)
{
    const int bh = blockIdx.y;            // 0..BS*NH-1
    const int b  = bh >> 4;               // / NH
    const int h  = bh & 15;               // % NH
    const int q0 = blockIdx.x * 128;
    const int tid = threadIdx.x;
    const int w   = tid >> 6;             // wave 0..3
    const int l   = tid & 63;             // lane
    const int g   = l >> 4;               // 0..3
    const int l15 = l & 15;

    __shared__ short Ks[64][72];          // K tile  [key][d]   bf16, padded
    __shared__ short Vt[64][72];          // V tile  [d][key]   bf16, padded
    __shared__ short PsA[4][16][72];      // per-wave P, half A
    __shared__ short PsB[4][16][72];      // per-wave P, half B
    __shared__ float mneg[64];            // 0 or -1e30 per key of this tile

    const short* __restrict__ Qh = q + (size_t)bh * QLEN * DH;
    const short* __restrict__ Kh = k + (size_t)bh * QLEN * DH;
    const short* __restrict__ Vh = v + (size_t)bh * QLEN * DH;

    // staging geometry
    const int krow0 = tid >> 3;           // K: rows krow0, krow0+32
    const int kcol  = (tid & 7) * 8;
    const int vr0   = (tid & 15) * 4;     // V: 4x4 block at (vr0, vc0)
    const int vc0   = (tid >> 4) * 4;

    // ---- Q B-fragments for both 16-row halves (held for whole kernel) ----
    bf16x8 qbA[2], qbB[2];
    {
        const short* qpA = Qh + (size_t)(q0 + w * 16 + l15) * DH;
        const short* qpB = qpA + (size_t)64 * DH;
        #pragma unroll
        for (int ks = 0; ks < 2; ++ks) {
            qbA[ks] = *reinterpret_cast<const bf16x8*>(qpA + ks * 32 + g * 8);
            qbB[ks] = *reinterpret_cast<const bf16x8*>(qpB + ks * 32 + g * 8);
        }
    }

    // ---- prefetch tile 0 into registers ----
    bf16x8 kr[2];
    bf16x4 vrg[4];
    int    mv = 0;
    #pragma unroll
    for (int it = 0; it < 2; ++it)
        kr[it] = *reinterpret_cast<const bf16x8*>(
            &Kh[(size_t)(it * 32 + krow0) * DH + kcol]);
    #pragma unroll
    for (int i = 0; i < 4; ++i)
        vrg[i] = *reinterpret_cast<const bf16x4*>(
            &Vh[(size_t)(vr0 + i) * DH + vc0]);
    if (tid < 64) mv = mask[b * QLEN + tid];

    f32x4 oA[4], oB[4];
    #pragma unroll
    for (int n = 0; n < 4; ++n) {
        oA[n] = (f32x4){0.f, 0.f, 0.f, 0.f};
        oB[n] = (f32x4){0.f, 0.f, 0.f, 0.f};
    }
    float mAx = -1e30f, lAx = 0.f;
    float mBx = -1e30f, lBx = 0.f;

    for (int kt = 0; kt < QLEN; kt += 64) {
        __syncthreads();   // previous tile's LDS reads complete

        // ---- write prefetched regs to LDS ----
        #pragma unroll
        for (int it = 0; it < 2; ++it)
            *reinterpret_cast<bf16x8*>(&Ks[it * 32 + krow0][kcol]) = kr[it];
        #pragma unroll
        for (int j = 0; j < 4; ++j) {
            bf16x4 wv = {vrg[0][j], vrg[1][j], vrg[2][j], vrg[3][j]};
            *reinterpret_cast<bf16x4*>(&Vt[vc0 + j][vr0]) = wv;
        }
        if (tid < 64) mneg[tid] = (mv == 0) ? -1e30f : 0.0f;

        // ---- issue next tile's global loads (latency hides under compute) --
        if (kt + 64 < QLEN) {
            #pragma unroll
            for (int it = 0; it < 2; ++it)
                kr[it] = *reinterpret_cast<const bf16x8*>(
                    &Kh[(size_t)(kt + 64 + it * 32 + krow0) * DH + kcol]);
            #pragma unroll
            for (int i = 0; i < 4; ++i)
                vrg[i] = *reinterpret_cast<const bf16x4*>(
                    &Vh[(size_t)(kt + 64 + vr0 + i) * DH + vc0]);
            if (tid < 64) mv = mask[b * QLEN + kt + 64 + tid];
        }
        __syncthreads();

        // ---- both 16-row halves, explicit names, separate Ps buffers ----
        FLASH_HALF(qbA, oA, mAx, lAx, PsA)
        FLASH_HALF(qbB, oB, mBx, lBx, PsB)
    }

    // ---- epilogue: normalize, write ctx (bf16) in [b][q][dim] ----
    {
        float ln[4];
        #pragma unroll
        for (int r = 0; r < 4; ++r) ln[r] = __shfl(lAx, g * 4 + r, 16);
        #pragma unroll
        for (int r = 0; r < 4; ++r) {
            const float inv  = 1.0f / ln[r];
            const int   qrow = q0 + w * 16 + g * 4 + r;
            #pragma unroll
            for (int n = 0; n < 4; ++n)
                ctx[((size_t)b * QLEN + qrow) * DIM + h * DH + n * 16 + l15] =
                    f2bf(oA[n][r] * inv);
        }
    }
    {
        float ln[4];
        #pragma unroll
        for (int r = 0; r < 4; ++r) ln[r] = __shfl(lBx, g * 4 + r, 16);
        #pragma unroll
        for (int r = 0; r < 4; ++r) {
            const float inv  = 1.0f / ln[r];
            const int   qrow = q0 + 64 + w * 16 + g * 4 + r;
            #pragma unroll
            for (int n = 0; n < 4; ++n)
                ctx[((size_t)b * QLEN + qrow) * DIM + h * DH + n * 16 + l15] =
                    f2bf(oB[n][r] * inv);
        }
    }
}

// ---------------------------------------------------------------------------
extern "C" void kernel_launch(void* const* d_in, const int* in_sizes, int n_in,
                              void* d_out, int out_size, void* d_ws, size_t ws_size,
                              hipStream_t stream)
{
    const float* x    = (const float*)d_in[0];
    const int*   mask = (const int*)  d_in[1];
    const float* wq   = (const float*)d_in[2];
    const float* bq   = (const float*)d_in[3];
    const float* wk   = (const float*)d_in[4];
    const float* bk   = (const float*)d_in[5];
    const float* wv   = (const float*)d_in[6];
    const float* bv   = (const float*)d_in[7];
    const float* wo   = (const float*)d_in[8];
    const float* bo   = (const float*)d_in[9];
    float* out = (float*)d_out;

    short* ws = (short*)d_ws;
    const size_t S  = (size_t)MROWS * DIM;     // 8.39M elements
    const size_t W2 = (size_t)DIM * DIM;       // 1.05M elements
    short* xb   = ws;
    short* wqb  = xb  + S;
    short* wkb  = wqb + W2;
    short* wvb  = wkb + W2;
    short* wob  = wvb + W2;
    short* qb   = wob + W2;
    short* kb   = qb  + S;
    short* vb   = kb  + S;
    short* ctxb = vb  + S;

    // 0) one-time fp32 -> bf16 conversion of x and weights
    dim3 gc(512, 5);
    cvt_bf16_all<<<gc, 256, 0, stream>>>(x, wq, wk, wv, wo,
                                         xb, wqb, wkb, wvb, wob);

    // 1) fused QKV projections (z selects Q/K/V), bf16 in/out
    dim3 gq(MROWS / 128, DIM / 128, 3);
    gemm_qkv_mfma<<<gq, 256, 0, stream>>>(xb, wqb, bq, wkb, bk, wvb, bv,
                                          qb, kb, vb);

    // 2) flash attention (bf16 MFMA, 128 q-rows/block)
    dim3 gf(QLEN / 128, BS * NH);
    flash_attn_mfma<<<gf, 256, 0, stream>>>(qb, kb, vb, mask, ctxb);

    // 3) output projection (bf16 A/B, fp32 out)
    dim3 go(MROWS / 128, DIM / 128);
    gemm_out_mfma<<<go, 256, 0, stream>>>(ctxb, wob, bo, out);
}